// Round 5
// baseline (125.735 us; speedup 1.0000x reference)
//
#include <hip/hip_runtime.h>

typedef __bf16 bf16_t;
typedef bf16_t bf16x8 __attribute__((ext_vector_type(8)));
typedef bf16_t bf16x4 __attribute__((ext_vector_type(4)));
typedef float  f32x4  __attribute__((ext_vector_type(4)));

#define MFMA32(a, b, c) __builtin_amdgcn_mfma_f32_16x16x32_bf16(a, b, c, 0, 0, 0)

typedef __attribute__((address_space(3))) unsigned int       lds_u32;
typedef __attribute__((address_space(1))) const unsigned int glb_u32c;
#define DMA16(GP, LP) __builtin_amdgcn_global_load_lds((glb_u32c*)(const void*)(GP), \
                                                       (lds_u32*)(void*)(LP), 16, 0, 0)

// ---------------- GN pass 1 (blocks 0-255) + weight prep (blocks 256-319) ----------------
__global__ __launch_bounds__(256) void gn1w_kernel(const float* __restrict__ x,
    float2* __restrict__ partials,
    const float* __restrict__ Wq, const float* __restrict__ Wk,
    const float* __restrict__ Wv, const float* __restrict__ Wo,
    bf16_t* __restrict__ Wt) {
  int blk = blockIdx.x, t = threadIdx.x;
  if (blk >= 256) {                       // weight transpose+bf16: Wt[w][c][k] = W_w[k][c]
    int idx = (blk - 256) * 256 + t;
    int wsel = idx >> 12, rem = idx & 4095;
    int c = rem >> 6, kk = rem & 63;
    const float* src = (wsel == 0) ? Wq : ((wsel == 1) ? Wk : ((wsel == 2) ? Wv : Wo));
    Wt[idx] = (bf16_t)src[kk * 64 + c];
    return;
  }
  const float4* x4 = (const float4*)x + (size_t)blk * 1024;
  float s = 0.f, sq = 0.f;
  #pragma unroll
  for (int u = 0; u < 4; ++u) {
    float4 v = x4[u * 256 + t];
    s  += v.x + v.y + v.z + v.w;
    sq += v.x * v.x + v.y * v.y + v.z * v.z + v.w * v.w;
  }
  for (int off = 32; off; off >>= 1) {
    s  += __shfl_down(s, off, 64);
    sq += __shfl_down(sq, off, 64);
  }
  __shared__ float2 ps[4];
  if ((t & 63) == 0) ps[t >> 6] = make_float2(s, sq);
  __syncthreads();
  if (t == 0) {
    float S = 0.f, Q = 0.f;
    #pragma unroll
    for (int i = 0; i < 4; ++i) { S += ps[i].x; Q += ps[i].y; }
    partials[blk] = make_float2(S, Q);
  }
}

// ---------------- Fused GN-normalize + QKV MFMA GEMM ----------------
// K and V are emitted as PRE-SWIZZLED 64-key tile images (8 KB each) so the flash
// kernel can stage them with global_load_lds (lane-linear DMA, no LDS-side swizzle):
//   K image: elem(key kk, c)  at tile*4096 + kk*64 + (((c>>3) ^ (kk&7))<<3) + (c&7)
//   V image: elem(c, key kk)  at tile*4096 + c*64  + ((u' ^ ((c&7)<<1))<<2) + (kk&3)
//     where u' = (kk>>5)*8 + ((kk>>2)&3)*2 + ((kk>>4)&1)
//   The u' ordering interleaves the two 16-key halves of each 32-key group so one
//   ds_read_b128 yields the exact k-slot permutation that matches the P^T fragment
//   produced by two consecutive 16-key QK MFMAs (PV runs as 16x16x32).
__global__ __launch_bounds__(256) void gnqkv_kernel(
    const float* __restrict__ x, const float* __restrict__ gamma,
    const float* __restrict__ beta, const float2* __restrict__ parts,
    const bf16_t* __restrict__ Wt,
    const float* __restrict__ bq, const float* __restrict__ bk, const float* __restrict__ bv,
    bf16_t* __restrict__ xnb, bf16_t* __restrict__ qo, bf16_t* __restrict__ ko,
    bf16_t* __restrict__ vo) {
  __shared__ __align__(16) bf16_t xl[4096];
  int blk = blockIdx.x, t = threadIdx.x;
  int grp = blk >> 3;
  float S = 0.f, Q = 0.f;
  #pragma unroll
  for (int i = 0; i < 8; ++i) { float2 p = parts[grp * 8 + i]; S += p.x; Q += p.y; }
  float mean = S * (1.f / 32768.f);
  float rstd = rsqrtf(Q * (1.f / 32768.f) - mean * mean + 1e-5f);
  int h = blk & 63;
  float ga = gamma[h] * rstd;
  float be = beta[h] - mean * ga;
  {
    int r = t >> 2, col0 = (t & 3) * 16;
    const float4* x4 = (const float4*)(x + (size_t)blk * 4096 + r * 64 + col0);
    bf16x8 pk0, pk1;
    float4 v0 = x4[0], v1 = x4[1], v2 = x4[2], v3 = x4[3];
    pk0[0] = (bf16_t)(v0.x * ga + be); pk0[1] = (bf16_t)(v0.y * ga + be);
    pk0[2] = (bf16_t)(v0.z * ga + be); pk0[3] = (bf16_t)(v0.w * ga + be);
    pk0[4] = (bf16_t)(v1.x * ga + be); pk0[5] = (bf16_t)(v1.y * ga + be);
    pk0[6] = (bf16_t)(v1.z * ga + be); pk0[7] = (bf16_t)(v1.w * ga + be);
    pk1[0] = (bf16_t)(v2.x * ga + be); pk1[1] = (bf16_t)(v2.y * ga + be);
    pk1[2] = (bf16_t)(v2.z * ga + be); pk1[3] = (bf16_t)(v2.w * ga + be);
    pk1[4] = (bf16_t)(v3.x * ga + be); pk1[5] = (bf16_t)(v3.y * ga + be);
    pk1[6] = (bf16_t)(v3.z * ga + be); pk1[7] = (bf16_t)(v3.w * ga + be);
    *(bf16x8*)&xnb[(size_t)blk * 4096 + r * 64 + col0]     = pk0;
    *(bf16x8*)&xnb[(size_t)blk * 4096 + r * 64 + col0 + 8] = pk1;
    int sw = r & 7, j0 = (t & 3) * 2;
    *(bf16x8*)&xl[r * 64 + ((j0 ^ sw) << 3)]       = pk0;
    *(bf16x8*)&xl[r * 64 + (((j0 + 1) ^ sw) << 3)] = pk1;
  }
  __syncthreads();
  int w = t >> 6, lane = t & 63, quad = lane >> 4, l16 = lane & 15;
  int rl = w * 16 + l16, sw2 = rl & 7;
  bf16x8 a0 = *(const bf16x8*)&xl[rl * 64 + ((quad ^ sw2) << 3)];
  bf16x8 a1 = *(const bf16x8*)&xl[rl * 64 + (((quad + 4) ^ sw2) << 3)];
  int m0 = blk * 64 + w * 16;
  int bi = blk >> 6;
  int tile = blk & 63;
  size_t tbase = (size_t)bi * 262144 + (size_t)tile * 4096;
  f32x4 zero = {0.f, 0.f, 0.f, 0.f};
  const float QSCALE = 0.125f * 1.44269504088896340736f;   // C^-0.5 * log2(e)
  #pragma unroll
  for (int outk = 0; outk < 3; ++outk) {
    const bf16_t* wt = Wt + outk * 4096;
    const float* bias = (outk == 0) ? bq : ((outk == 1) ? bk : bv);
    #pragma unroll
    for (int nt = 0; nt < 4; ++nt) {
      int col = nt * 16 + l16;
      bf16x8 b0 = *(const bf16x8*)&wt[col * 64 + quad * 8];
      bf16x8 b1 = *(const bf16x8*)&wt[col * 64 + 32 + quad * 8];
      f32x4 acc = MFMA32(a0, b0, zero);
      acc = MFMA32(a1, b1, acc);
      float bb = bias[col];
      if (outk == 0) {
        #pragma unroll
        for (int r = 0; r < 4; ++r) {
          int m = m0 + quad * 4 + r;
          qo[(size_t)m * 64 + col] = (bf16_t)((acc[r] + bb) * QSCALE);
        }
      } else if (outk == 1) {
        // K tile image (swizzled): key kk = w*16+quad*4+r
        #pragma unroll
        for (int r = 0; r < 4; ++r) {
          int kk = (m0 & 63) + quad * 4 + r;
          ko[tbase + kk * 64 + ((((col >> 3) ^ (kk & 7)) << 3) | (col & 7))]
              = (bf16_t)(acc[r] + bb);
        }
      } else {
        // V tile image (swizzled, PV-k-slot-permuted unit order):
        // keys kk = w*16 + quad*4 + r  ->  u' = (w>>1)*8 + quad*2 + (w&1)
        bf16x4 pk;
        #pragma unroll
        for (int r = 0; r < 4; ++r) pk[r] = (bf16_t)(acc[r] + bb);
        int u = (w >> 1) * 8 + quad * 2 + (w & 1);
        *(bf16x4*)&vo[tbase + col * 64 + ((u ^ ((col & 7) << 1)) << 2)] = pk;
      }
    }
  }
}

// ---------------- Flash attention: DMA-staged 128-key tiles, 4-wave blocks ----------------
// grid (4, 16, 8) = (batch, qblock256, splitK) -> all 8 splits of a (b,qb) share one XCD
// (linear id diff = 64*sp ≡ 0 mod 8) so the Q re-fetch is L2-local.
// Block = 256 threads = 4 waves; wave w owns 64 queries q0 = qb*256 + w*64 (qt=0..3):
// halves the per-CU LDS broadcast amplification vs 32 q/wave (K/V frags feed 4 qt).
// REGISTER BUDGET (the round-1/3 bug): this wave shape needs ~158 VGPRs (o[4][4]=64,
// qf[4][2]=32, kf+va8=32, ~30 misc). __launch_bounds__(256,2) capped the allocator at
// 128 (CUDA min-blocks semantics -> 4 waves/SIMD -> 512/4) and the ~30-reg overflow
// spilled to scratch INSIDE the K-loop: ~104 MB of stray HBM writes (the mystery
// WRITE_SIZE=120MB) and +20 us. Fix: __launch_bounds__(256,1) -> cap 256 VGPR.
// Occupancy is LDS-limited anyway: 64 KB -> 2 blocks/CU = 8 waves/CU = 2 waves/SIMD,
// which at <=256 VGPR/wave fits the 512-reg/SIMD file exactly.
// Block streams 512 keys as 4 x 128-key tiles (2 pre-swizzled 64-key images, 16 KB),
// double-buffered. Staging is pure DMA (8 x 16B per wave per tile) issued before
// compute on the current tile; ONE __syncthreads per iteration.
// Core per 32-key step: S^T = mfma32(A=K-frag, B=Q-frag) x2 (two 16-key halves);
// P^T = exp2(S^T) packed to one bf16x8 (k-slot order matches V image unit permutation);
// O^T += mfma32(A=V^T-frag b128, B=P^T). Fixed-max softmax (M=0).
// Epilogue: O^T transposed through LDS (reusing Kb, 32 KB) so Opb stores are
// 1 KB-contiguous per wave instruction (full-line HBM writes; no write amplification).
__global__ __launch_bounds__(256, 1) void flash_kernel(
    const bf16_t* __restrict__ q, const bf16_t* __restrict__ k,
    const bf16_t* __restrict__ vp, bf16_t* __restrict__ Opb, float* __restrict__ ml) {
  __shared__ __align__(16) bf16_t Kb[2][8192];
  __shared__ __align__(16) bf16_t Vb[2][8192];
  int t = threadIdx.x;                  // 0..255
  int w = t >> 6, lane = t & 63, quad = lane >> 4, l16 = lane & 15;
  int b = blockIdx.x, qb = blockIdx.y, sp = blockIdx.z;
  int q0 = qb * 256 + w * 64;           // this wave's 64 queries (batch-local)

  bf16x8 qf[4][2];                      // Q B-frags: B[k=c][n=q]
  {
    const bf16_t* qp = q + ((size_t)b * 4096 + q0 + l16) * 64;
    #pragma unroll
    for (int qt = 0; qt < 4; ++qt)
      #pragma unroll
      for (int hh = 0; hh < 2; ++hh)
        qf[qt][hh] = *(const bf16x8*)&qp[qt * 1024 + hh * 32 + quad * 8];
  }
  f32x4 o[4][4];                        // O^T tiles: row=c, col=q
  f32x4 zero = {0.f, 0.f, 0.f, 0.f};
  #pragma unroll
  for (int qt = 0; qt < 4; ++qt)
    #pragma unroll
    for (int ct = 0; ct < 4; ++ct) o[qt][ct] = zero;
  float rs[4] = {0.f, 0.f, 0.f, 0.f};

  // 8 pre-swizzled 4096-elem tile images per (b, sp); 128-key tile = 2 images (8192).
  // Wave w DMAs its quarter (2048 elems = 4 x 1 KB) of each 16 KB tile.
  const bf16_t* kimg = k  + (size_t)b * 262144 + (size_t)sp * 32768 + w * 2048 + lane * 8;
  const bf16_t* vimg = vp + (size_t)b * 262144 + (size_t)sp * 32768 + w * 2048 + lane * 8;

  // prologue: DMA tile 0 into buffer 0
  #pragma unroll
  for (int i = 0; i < 4; ++i) {
    DMA16(kimg + i * 512, &Kb[0][w * 2048 + i * 512]);
    DMA16(vimg + i * 512, &Vb[0][w * 2048 + i * 512]);
  }
  __syncthreads();

  int swk = l16 & 7;                    // K-read swizzle
  int swv = (l16 & 7) << 1;             // V-read swizzle (even => b128 stays aligned)

  for (int it = 0; it < 4; ++it) {
    int cur = it & 1;
    if (it < 3) {                       // DMA next 128-key tile into other buffer
      const bf16_t* kg = kimg + (it + 1) * 8192;
      const bf16_t* vg = vimg + (it + 1) * 8192;
      int nxt = cur ^ 1;
      #pragma unroll
      for (int i = 0; i < 4; ++i) {
        DMA16(kg + i * 512, &Kb[nxt][w * 2048 + i * 512]);
        DMA16(vg + i * 512, &Vb[nxt][w * 2048 + i * 512]);
      }
    }
    #pragma unroll
    for (int j = 0; j < 4; ++j) {       // 32-key steps within the 128-key tile
      const bf16_t* Kh = &Kb[cur][(j >> 1) * 4096];
      const bf16_t* Vh = &Vb[cur][(j >> 1) * 4096];
      int k2 = j & 1;                   // which 32-key half of the 64-key image
      int krow_a = ((k2 * 2) * 16 + l16) * 64;
      int krow_b = ((k2 * 2 + 1) * 16 + l16) * 64;
      bf16x8 kf0a = *(const bf16x8*)&Kh[krow_a + ((quad ^ swk) << 3)];
      bf16x8 kf1a = *(const bf16x8*)&Kh[krow_a + (((quad + 4) ^ swk) << 3)];
      bf16x8 kf0b = *(const bf16x8*)&Kh[krow_b + ((quad ^ swk) << 3)];
      bf16x8 kf1b = *(const bf16x8*)&Kh[krow_b + (((quad + 4) ^ swk) << 3)];
      int ub = k2 * 8 + quad * 2;       // even unit base -> b128 aligned after XOR
      bf16x8 va8[4];                    // V^T A-frags: A[m=c][k-slot], 32-key chunk
      #pragma unroll
      for (int ct = 0; ct < 4; ++ct)
        va8[ct] = *(const bf16x8*)&Vh[(ct * 16 + l16) * 64 + ((ub ^ swv) << 2)];
      #pragma unroll
      for (int qt = 0; qt < 4; ++qt) {
        f32x4 sta = MFMA32(kf0a, qf[qt][0], zero);
        sta = MFMA32(kf1a, qf[qt][1], sta);           // S^T[key][q], first 16 keys
        f32x4 stb = MFMA32(kf0b, qf[qt][0], zero);
        stb = MFMA32(kf1b, qf[qt][1], stb);           // second 16 keys
        bf16x8 pb;                                    // P^T: e0..3 half a, e4..7 half b
        float psum = 0.f;
        #pragma unroll
        for (int r = 0; r < 4; ++r) {
          float pa = __builtin_amdgcn_exp2f(sta[r]);
          float pc = __builtin_amdgcn_exp2f(stb[r]);
          psum += pa + pc;
          pb[r]     = (bf16_t)pa;
          pb[r + 4] = (bf16_t)pc;
        }
        rs[qt] += psum;
        #pragma unroll
        for (int ct = 0; ct < 4; ++ct)
          o[qt][ct] = MFMA32(va8[ct], pb, o[qt][ct]);
      }
    }
    __syncthreads();                    // drains DMA (vmcnt) + aligns buffer swap
  }

  // rowsums: sum over the 4 quads (each held distinct keys)
  #pragma unroll
  for (int qt = 0; qt < 4; ++qt) {
    rs[qt] += __shfl_xor(rs[qt], 16, 64);
    rs[qt] += __shfl_xor(rs[qt], 32, 64);
  }
  // rowsum store: 64 B-aligned contiguous 16-float lines
  size_t rbase = (size_t)sp * 16384 + (size_t)b * 4096 + q0;
  #pragma unroll
  for (int qt = 0; qt < 4; ++qt)
    if (quad == 0) ml[rbase + qt * 16 + l16] = rs[qt];

  // ---- coalesced epilogue: transpose O^T -> row-major via LDS (reuse Kb, 32 KB) ----
  // write side: per (qt,ct) one bf16x4 to row R = w*64+qt*16+l16, chunk-swizzled
  bf16_t* Ot = (bf16_t*)Kb;             // [256 rows][64 c], 16B chunks XOR-swizzled by R&7
  #pragma unroll
  for (int qt = 0; qt < 4; ++qt) {
    int R = w * 64 + qt * 16 + l16;
    int swz = l16 & 7;                  // == R & 7
    #pragma unroll
    for (int ct = 0; ct < 4; ++ct) {
      bf16x4 pk;
      #pragma unroll
      for (int r = 0; r < 4; ++r) pk[r] = (bf16_t)o[qt][ct][r];
      int ch = ct * 2 + (quad >> 1);
      *(bf16x4*)&Ot[R * 64 + ((ch ^ swz) << 3) + ((quad & 1) << 2)] = pk;
    }
  }
  __syncthreads();
  // read side: lane t, instr j -> 16 B of row (j*32 + t/8); global store is 1 KB
  // contiguous per wave instruction (full-line HBM writes)
  size_t obase = ((size_t)sp * 16384 + (size_t)b * 4096 + (size_t)qb * 256) * 64;
  #pragma unroll
  for (int j = 0; j < 8; ++j) {
    int R = j * 32 + (t >> 3);
    int ch = (t & 7) ^ ((t >> 3) & 7);
    bf16x8 vv = *(const bf16x8*)&Ot[R * 64 + (ch << 3)];
    *(bf16x8*)&Opb[obase + j * 2048 + t * 8] = vv;
  }
}

// ---------------- Combine 8 splits + output projection + residual ----------------
__global__ __launch_bounds__(256) void proj_kernel(
    const bf16_t* __restrict__ Opb, const float* __restrict__ ml,
    const bf16_t* __restrict__ Wt, const float* __restrict__ bo,
    const bf16_t* __restrict__ xnb, float* __restrict__ out) {
  int t = threadIdx.x, w = t >> 6, lane = t & 63, quad = lane >> 4, l16 = lane & 15;
  int r0 = blockIdx.x * 64 + w * 16;                 // global row base (0..16383)
  float acc0[8], acc1[8];
  #pragma unroll
  for (int e = 0; e < 8; ++e) { acc0[e] = 0.f; acc1[e] = 0.f; }
  float lsum = 0.f;
  #pragma unroll
  for (int s = 0; s < 8; ++s) {
    size_t rr = (size_t)s * 16384 + r0 + l16;
    bf16x8 f0 = *(const bf16x8*)&Opb[rr * 64 + quad * 8];
    bf16x8 f1 = *(const bf16x8*)&Opb[rr * 64 + 32 + quad * 8];
    #pragma unroll
    for (int e = 0; e < 8; ++e) { acc0[e] += (float)f0[e]; acc1[e] += (float)f1[e]; }
    lsum += ml[rr];
  }
  float linv = 1.f / lsum;
  bf16x8 a0, a1;
  #pragma unroll
  for (int e = 0; e < 8; ++e) {
    a0[e] = (bf16_t)(acc0[e] * linv);
    a1[e] = (bf16_t)(acc1[e] * linv);
  }
  f32x4 zero = {0.f, 0.f, 0.f, 0.f};
  const bf16_t* wt = Wt + 3 * 4096;                  // Wo^T
  #pragma unroll
  for (int nt = 0; nt < 4; ++nt) {
    int col = nt * 16 + l16;
    bf16x8 b0 = *(const bf16x8*)&wt[col * 64 + quad * 8];
    bf16x8 b1 = *(const bf16x8*)&wt[col * 64 + 32 + quad * 8];
    f32x4 acc = MFMA32(a0, b0, zero);
    acc = MFMA32(a1, b1, acc);
    float bb = bo[col];
    #pragma unroll
    for (int r = 0; r < 4; ++r) {
      size_t m = (size_t)r0 + quad * 4 + r;
      out[m * 64 + col] = acc[r] + bb + (float)xnb[m * 64 + col];
    }
  }
}

extern "C" void kernel_launch(void* const* d_in, const int* in_sizes, int n_in,
                              void* d_out, int out_size, void* d_ws, size_t ws_size,
                              hipStream_t stream) {
  const float* x     = (const float*)d_in[0];
  const float* gamma = (const float*)d_in[1];
  const float* beta  = (const float*)d_in[2];
  const float* Wq    = (const float*)d_in[3];
  const float* bq    = (const float*)d_in[4];
  const float* Wk    = (const float*)d_in[5];
  const float* bk    = (const float*)d_in[6];
  const float* Wv    = (const float*)d_in[7];
  const float* bv    = (const float*)d_in[8];
  const float* Wo    = (const float*)d_in[9];
  const float* bo    = (const float*)d_in[10];
  float* out = (float*)d_out;

  char* ws = (char*)d_ws;
  bf16_t* xnb   = (bf16_t*)(ws + 0);                    // 2 MB
  bf16_t* qbuf  = (bf16_t*)(ws + (2u  << 20));          // 2 MB
  bf16_t* kbuf  = (bf16_t*)(ws + (4u  << 20));          // 2 MB (swizzled tile images)
  bf16_t* vbuf  = (bf16_t*)(ws + (6u  << 20));          // 2 MB (swizzled tile images)
  bf16_t* Opb   = (bf16_t*)(ws + (8u  << 20));          // 16 MB (8 splits)
  float*  ml    = (float*)(ws + (24u << 20));           // 512 KB
  float2* parts = (float2*)(ws + (25u << 20));          // 2 KB
  bf16_t* Wt    = (bf16_t*)(ws + (25u << 20) + 4096);   // 32 KB

  hipLaunchKernelGGL(gn1w_kernel,  dim3(320),       dim3(256), 0, stream, x, parts, Wq, Wk, Wv, Wo, Wt);
  hipLaunchKernelGGL(gnqkv_kernel, dim3(256),       dim3(256), 0, stream, x, gamma, beta, parts, Wt, bq, bk, bv, xnb, qbuf, kbuf, vbuf);
  hipLaunchKernelGGL(flash_kernel, dim3(4, 16, 8),  dim3(256), 0, stream, qbuf, kbuf, vbuf, Opb, ml);
  hipLaunchKernelGGL(proj_kernel,  dim3(256),       dim3(256), 0, stream, Opb, ml, Wt, bo, xnb, out);
}

// Round 6
// 116.297 us; speedup vs baseline: 1.0812x; 1.0812x over previous
//
#include <hip/hip_runtime.h>

typedef __bf16 bf16_t;
typedef bf16_t bf16x8 __attribute__((ext_vector_type(8)));
typedef bf16_t bf16x4 __attribute__((ext_vector_type(4)));
typedef float  f32x4  __attribute__((ext_vector_type(4)));

#define MFMA32(a, b, c) __builtin_amdgcn_mfma_f32_16x16x32_bf16(a, b, c, 0, 0, 0)

typedef __attribute__((address_space(3))) unsigned int       lds_u32;
typedef __attribute__((address_space(1))) const unsigned int glb_u32c;
#define DMA16(GP, LP) __builtin_amdgcn_global_load_lds((glb_u32c*)(const void*)(GP), \
                                                       (lds_u32*)(void*)(LP), 16, 0, 0)

// ---------------- GN pass 1 (blocks 0-255) + weight prep (blocks 256-319) ----------------
__global__ __launch_bounds__(256) void gn1w_kernel(const float* __restrict__ x,
    float2* __restrict__ partials,
    const float* __restrict__ Wq, const float* __restrict__ Wk,
    const float* __restrict__ Wv, const float* __restrict__ Wo,
    bf16_t* __restrict__ Wt) {
  int blk = blockIdx.x, t = threadIdx.x;
  if (blk >= 256) {                       // weight transpose+bf16: Wt[w][c][k] = W_w[k][c]
    int idx = (blk - 256) * 256 + t;
    int wsel = idx >> 12, rem = idx & 4095;
    int c = rem >> 6, kk = rem & 63;
    const float* src = (wsel == 0) ? Wq : ((wsel == 1) ? Wk : ((wsel == 2) ? Wv : Wo));
    Wt[idx] = (bf16_t)src[kk * 64 + c];
    return;
  }
  const float4* x4 = (const float4*)x + (size_t)blk * 1024;
  float s = 0.f, sq = 0.f;
  #pragma unroll
  for (int u = 0; u < 4; ++u) {
    float4 v = x4[u * 256 + t];
    s  += v.x + v.y + v.z + v.w;
    sq += v.x * v.x + v.y * v.y + v.z * v.z + v.w * v.w;
  }
  for (int off = 32; off; off >>= 1) {
    s  += __shfl_down(s, off, 64);
    sq += __shfl_down(sq, off, 64);
  }
  __shared__ float2 ps[4];
  if ((t & 63) == 0) ps[t >> 6] = make_float2(s, sq);
  __syncthreads();
  if (t == 0) {
    float S = 0.f, Q = 0.f;
    #pragma unroll
    for (int i = 0; i < 4; ++i) { S += ps[i].x; Q += ps[i].y; }
    partials[blk] = make_float2(S, Q);
  }
}

// ---------------- Fused GN-normalize + QKV MFMA GEMM ----------------
// K and V are emitted as PRE-SWIZZLED 64-key tile images (8 KB each) so the flash
// kernel can stage them with global_load_lds (lane-linear DMA, no LDS-side swizzle):
//   K image: elem(key kk, c)  at tile*4096 + kk*64 + (((c>>3) ^ (kk&7))<<3) + (c&7)
//   V image: elem(c, key kk)  at tile*4096 + c*64  + ((u' ^ ((c&7)<<1))<<2) + (kk&3)
//     where u' = (kk>>5)*8 + ((kk>>2)&3)*2 + ((kk>>4)&1)
//   The u' ordering interleaves the two 16-key halves of each 32-key group so one
//   ds_read_b128 yields the exact k-slot permutation that matches the P^T fragment
//   produced by two consecutive 16-key QK MFMAs (PV runs as 16x16x32).
__global__ __launch_bounds__(256) void gnqkv_kernel(
    const float* __restrict__ x, const float* __restrict__ gamma,
    const float* __restrict__ beta, const float2* __restrict__ parts,
    const bf16_t* __restrict__ Wt,
    const float* __restrict__ bq, const float* __restrict__ bk, const float* __restrict__ bv,
    bf16_t* __restrict__ xnb, bf16_t* __restrict__ qo, bf16_t* __restrict__ ko,
    bf16_t* __restrict__ vo) {
  __shared__ __align__(16) bf16_t xl[4096];
  int blk = blockIdx.x, t = threadIdx.x;
  int grp = blk >> 3;
  float S = 0.f, Q = 0.f;
  #pragma unroll
  for (int i = 0; i < 8; ++i) { float2 p = parts[grp * 8 + i]; S += p.x; Q += p.y; }
  float mean = S * (1.f / 32768.f);
  float rstd = rsqrtf(Q * (1.f / 32768.f) - mean * mean + 1e-5f);
  int h = blk & 63;
  float ga = gamma[h] * rstd;
  float be = beta[h] - mean * ga;
  {
    int r = t >> 2, col0 = (t & 3) * 16;
    const float4* x4 = (const float4*)(x + (size_t)blk * 4096 + r * 64 + col0);
    bf16x8 pk0, pk1;
    float4 v0 = x4[0], v1 = x4[1], v2 = x4[2], v3 = x4[3];
    pk0[0] = (bf16_t)(v0.x * ga + be); pk0[1] = (bf16_t)(v0.y * ga + be);
    pk0[2] = (bf16_t)(v0.z * ga + be); pk0[3] = (bf16_t)(v0.w * ga + be);
    pk0[4] = (bf16_t)(v1.x * ga + be); pk0[5] = (bf16_t)(v1.y * ga + be);
    pk0[6] = (bf16_t)(v1.z * ga + be); pk0[7] = (bf16_t)(v1.w * ga + be);
    pk1[0] = (bf16_t)(v2.x * ga + be); pk1[1] = (bf16_t)(v2.y * ga + be);
    pk1[2] = (bf16_t)(v2.z * ga + be); pk1[3] = (bf16_t)(v2.w * ga + be);
    pk1[4] = (bf16_t)(v3.x * ga + be); pk1[5] = (bf16_t)(v3.y * ga + be);
    pk1[6] = (bf16_t)(v3.z * ga + be); pk1[7] = (bf16_t)(v3.w * ga + be);
    *(bf16x8*)&xnb[(size_t)blk * 4096 + r * 64 + col0]     = pk0;
    *(bf16x8*)&xnb[(size_t)blk * 4096 + r * 64 + col0 + 8] = pk1;
    int sw = r & 7, j0 = (t & 3) * 2;
    *(bf16x8*)&xl[r * 64 + ((j0 ^ sw) << 3)]       = pk0;
    *(bf16x8*)&xl[r * 64 + (((j0 + 1) ^ sw) << 3)] = pk1;
  }
  __syncthreads();
  int w = t >> 6, lane = t & 63, quad = lane >> 4, l16 = lane & 15;
  int rl = w * 16 + l16, sw2 = rl & 7;
  bf16x8 a0 = *(const bf16x8*)&xl[rl * 64 + ((quad ^ sw2) << 3)];
  bf16x8 a1 = *(const bf16x8*)&xl[rl * 64 + (((quad + 4) ^ sw2) << 3)];
  int m0 = blk * 64 + w * 16;
  int bi = blk >> 6;
  int tile = blk & 63;
  size_t tbase = (size_t)bi * 262144 + (size_t)tile * 4096;
  f32x4 zero = {0.f, 0.f, 0.f, 0.f};
  const float QSCALE = 0.125f * 1.44269504088896340736f;   // C^-0.5 * log2(e)
  #pragma unroll
  for (int outk = 0; outk < 3; ++outk) {
    const bf16_t* wt = Wt + outk * 4096;
    const float* bias = (outk == 0) ? bq : ((outk == 1) ? bk : bv);
    #pragma unroll
    for (int nt = 0; nt < 4; ++nt) {
      int col = nt * 16 + l16;
      bf16x8 b0 = *(const bf16x8*)&wt[col * 64 + quad * 8];
      bf16x8 b1 = *(const bf16x8*)&wt[col * 64 + 32 + quad * 8];
      f32x4 acc = MFMA32(a0, b0, zero);
      acc = MFMA32(a1, b1, acc);
      float bb = bias[col];
      if (outk == 0) {
        #pragma unroll
        for (int r = 0; r < 4; ++r) {
          int m = m0 + quad * 4 + r;
          qo[(size_t)m * 64 + col] = (bf16_t)((acc[r] + bb) * QSCALE);
        }
      } else if (outk == 1) {
        // K tile image (swizzled): key kk = w*16+quad*4+r
        #pragma unroll
        for (int r = 0; r < 4; ++r) {
          int kk = (m0 & 63) + quad * 4 + r;
          ko[tbase + kk * 64 + ((((col >> 3) ^ (kk & 7)) << 3) | (col & 7))]
              = (bf16_t)(acc[r] + bb);
        }
      } else {
        // V tile image (swizzled, PV-k-slot-permuted unit order):
        // keys kk = w*16 + quad*4 + r  ->  u' = (w>>1)*8 + quad*2 + (w&1)
        bf16x4 pk;
        #pragma unroll
        for (int r = 0; r < 4; ++r) pk[r] = (bf16_t)(acc[r] + bb);
        int u = (w >> 1) * 8 + quad * 2 + (w & 1);
        *(bf16x4*)&vo[tbase + col * 64 + ((u ^ ((col & 7) << 1)) << 2)] = pk;
      }
    }
  }
}

// ---------------- Flash attention: 64-key double-buffer, 4 blocks/CU ----------------
// grid (4, 32, 8) = (batch, qblock128, splitK); all 8 splits of a (b,qb) share one XCD
// (linear id diff = 128*sp ≡ 0 mod 8) so the Q re-fetch is L2-local.
// Block = 256 threads = 4 waves; wave w owns 32 queries q0 = qb*128 + w*32 -- the exact
// R2 body (proven to fit the 128-VGPR budget with zero spill).
// OCCUPANCY is the change this round: flash was latency-bound (all pipes <20%) at
// 2 blocks/CU (64 KB LDS) = 2 waves/SIMD. Halving LDS to 32 KB (double-buffered
// 64-KEY images instead of 128-key tiles) + split-8 (1024 blocks) gives 4 blocks/CU
// = 4 waves/SIMD -- 2x the latency hiding. __launch_bounds__(256,4) pins the 128-VGPR
// cap this body already meets (do NOT put more per-wave state in this kernel).
// Staging is pure DMA (4 x 16B per thread per image) issued before compute on the
// current image; ONE __syncthreads per 64-key iteration.
// Core per 32-key step: S^T = mfma32(A=K-frag, B=Q-frag) x2 (two 16-key halves);
// P^T = exp2(S^T) packed to one bf16x8 (k-slot order matches V image unit permutation);
// O^T += mfma32(A=V^T-frag b128, B=P^T). Fixed-max softmax (M=0).
// Epilogue: O^T transposed through LDS (reusing Kb, exactly 16 KB) so Opb stores are
// 1 KB-contiguous per wave instruction (full-line HBM writes; no write amplification).
__global__ __launch_bounds__(256, 4) void flash_kernel(
    const bf16_t* __restrict__ q, const bf16_t* __restrict__ k,
    const bf16_t* __restrict__ vp, bf16_t* __restrict__ Opb, float* __restrict__ ml) {
  __shared__ __align__(16) bf16_t Kb[2][4096];
  __shared__ __align__(16) bf16_t Vb[2][4096];
  int t = threadIdx.x;                  // 0..255
  int w = t >> 6, lane = t & 63, quad = lane >> 4, l16 = lane & 15;
  int b = blockIdx.x, qb = blockIdx.y, sp = blockIdx.z;
  int q0 = qb * 128 + w * 32;           // this wave's 32 queries (batch-local)

  bf16x8 qf[2][2];                      // Q B-frags: B[k=c][n=q]
  {
    const bf16_t* qp = q + ((size_t)b * 4096 + q0 + l16) * 64;
    #pragma unroll
    for (int qt = 0; qt < 2; ++qt)
      #pragma unroll
      for (int hh = 0; hh < 2; ++hh)
        qf[qt][hh] = *(const bf16x8*)&qp[qt * 1024 + hh * 32 + quad * 8];
  }
  f32x4 o[2][4];                        // O^T tiles: row=c, col=q
  f32x4 zero = {0.f, 0.f, 0.f, 0.f};
  #pragma unroll
  for (int qt = 0; qt < 2; ++qt)
    #pragma unroll
    for (int ct = 0; ct < 4; ++ct) o[qt][ct] = zero;
  float rs[2] = {0.f, 0.f};

  // 8 pre-swizzled 4096-elem images per (b, sp). Wave w DMAs its quarter (1024 elems
  // = 2 x 1 KB chunks) of each 8 KB image; 4 DMA16 per thread per image (K2 + V2).
  const bf16_t* kimg = k  + (size_t)b * 262144 + (size_t)sp * 32768 + w * 1024 + lane * 8;
  const bf16_t* vimg = vp + (size_t)b * 262144 + (size_t)sp * 32768 + w * 1024 + lane * 8;

  auto stage = [&](int img, int buf) {
    const bf16_t* kg = kimg + img * 4096;
    const bf16_t* vg = vimg + img * 4096;
    DMA16(kg,       &Kb[buf][w * 1024]);
    DMA16(kg + 512, &Kb[buf][w * 1024 + 512]);
    DMA16(vg,       &Vb[buf][w * 1024]);
    DMA16(vg + 512, &Vb[buf][w * 1024 + 512]);
  };

  stage(0, 0);
  __syncthreads();

  int swk = l16 & 7;                    // K-read swizzle
  int swv = (l16 & 7) << 1;             // V-read swizzle (even => b128 stays aligned)

  for (int img = 0; img < 8; ++img) {
    int cur = img & 1;
    if (img < 7) stage(img + 1, cur ^ 1);   // prefetch next image into other buffer
    const bf16_t* Kh = Kb[cur];
    const bf16_t* Vh = Vb[cur];
    #pragma unroll
    for (int k2 = 0; k2 < 2; ++k2) {    // two 32-key steps within the 64-key image
      int krow_a = ((k2 * 2) * 16 + l16) * 64;
      int krow_b = ((k2 * 2 + 1) * 16 + l16) * 64;
      bf16x8 kf0a = *(const bf16x8*)&Kh[krow_a + ((quad ^ swk) << 3)];
      bf16x8 kf1a = *(const bf16x8*)&Kh[krow_a + (((quad + 4) ^ swk) << 3)];
      bf16x8 kf0b = *(const bf16x8*)&Kh[krow_b + ((quad ^ swk) << 3)];
      bf16x8 kf1b = *(const bf16x8*)&Kh[krow_b + (((quad + 4) ^ swk) << 3)];
      int ub = k2 * 8 + quad * 2;       // even unit base -> b128 aligned after XOR
      bf16x8 va8[4];                    // V^T A-frags: A[m=c][k-slot], 32-key chunk
      #pragma unroll
      for (int ct = 0; ct < 4; ++ct)
        va8[ct] = *(const bf16x8*)&Vh[(ct * 16 + l16) * 64 + ((ub ^ swv) << 2)];
      #pragma unroll
      for (int qt = 0; qt < 2; ++qt) {
        f32x4 sta = MFMA32(kf0a, qf[qt][0], zero);
        sta = MFMA32(kf1a, qf[qt][1], sta);           // S^T[key][q], first 16 keys
        f32x4 stb = MFMA32(kf0b, qf[qt][0], zero);
        stb = MFMA32(kf1b, qf[qt][1], stb);           // second 16 keys
        bf16x8 pb;                                    // P^T: e0..3 half a, e4..7 half b
        float psum = 0.f;
        #pragma unroll
        for (int r = 0; r < 4; ++r) {
          float pa = __builtin_amdgcn_exp2f(sta[r]);
          float pc = __builtin_amdgcn_exp2f(stb[r]);
          psum += pa + pc;
          pb[r]     = (bf16_t)pa;
          pb[r + 4] = (bf16_t)pc;
        }
        rs[qt] += psum;
        #pragma unroll
        for (int ct = 0; ct < 4; ++ct)
          o[qt][ct] = MFMA32(va8[ct], pb, o[qt][ct]);
      }
    }
    __syncthreads();                    // drains DMA (vmcnt) + aligns buffer swap
  }

  // rowsums: sum over the 4 quads (each held distinct keys)
  #pragma unroll
  for (int qt = 0; qt < 2; ++qt) {
    rs[qt] += __shfl_xor(rs[qt], 16, 64);
    rs[qt] += __shfl_xor(rs[qt], 32, 64);
  }
  // rowsum store: 64 B-aligned contiguous 16-float lines
  size_t rbase = (size_t)sp * 16384 + (size_t)b * 4096 + q0;
  #pragma unroll
  for (int qt = 0; qt < 2; ++qt)
    if (quad == 0) ml[rbase + qt * 16 + l16] = rs[qt];

  // ---- coalesced epilogue: transpose O^T -> row-major via LDS (reuse Kb, 16 KB) ----
  // write side: per (qt,ct) one bf16x4 to row R = w*32+qt*16+l16, chunk-swizzled
  bf16_t* Ot = (bf16_t*)Kb;             // [128 rows][64 c], 16B chunks XOR-swizzled by R&7
  #pragma unroll
  for (int qt = 0; qt < 2; ++qt) {
    int R = w * 32 + qt * 16 + l16;
    int swz = l16 & 7;                  // == R & 7
    #pragma unroll
    for (int ct = 0; ct < 4; ++ct) {
      bf16x4 pk;
      #pragma unroll
      for (int r = 0; r < 4; ++r) pk[r] = (bf16_t)o[qt][ct][r];
      int ch = ct * 2 + (quad >> 1);
      *(bf16x4*)&Ot[R * 64 + ((ch ^ swz) << 3) + ((quad & 1) << 2)] = pk;
    }
  }
  __syncthreads();
  // read side: lane t, instr j -> 16 B of row (j*32 + t/8); global store is 1 KB
  // contiguous per wave instruction (full-line HBM writes)
  size_t obase = ((size_t)sp * 16384 + (size_t)b * 4096 + (size_t)qb * 128) * 64;
  #pragma unroll
  for (int j = 0; j < 4; ++j) {
    int R = j * 32 + (t >> 3);
    int ch = (t & 7) ^ ((t >> 3) & 7);
    bf16x8 vv = *(const bf16x8*)&Ot[R * 64 + (ch << 3)];
    *(bf16x8*)&Opb[obase + j * 2048 + t * 8] = vv;
  }
}

// ---------------- Combine 8 splits + output projection + residual ----------------
__global__ __launch_bounds__(256) void proj_kernel(
    const bf16_t* __restrict__ Opb, const float* __restrict__ ml,
    const bf16_t* __restrict__ Wt, const float* __restrict__ bo,
    const bf16_t* __restrict__ xnb, float* __restrict__ out) {
  int t = threadIdx.x, w = t >> 6, lane = t & 63, quad = lane >> 4, l16 = lane & 15;
  int r0 = blockIdx.x * 64 + w * 16;                 // global row base (0..16383)
  float acc0[8], acc1[8];
  #pragma unroll
  for (int e = 0; e < 8; ++e) { acc0[e] = 0.f; acc1[e] = 0.f; }
  float lsum = 0.f;
  #pragma unroll
  for (int s = 0; s < 8; ++s) {
    size_t rr = (size_t)s * 16384 + r0 + l16;
    bf16x8 f0 = *(const bf16x8*)&Opb[rr * 64 + quad * 8];
    bf16x8 f1 = *(const bf16x8*)&Opb[rr * 64 + 32 + quad * 8];
    #pragma unroll
    for (int e = 0; e < 8; ++e) { acc0[e] += (float)f0[e]; acc1[e] += (float)f1[e]; }
    lsum += ml[rr];
  }
  float linv = 1.f / lsum;
  bf16x8 a0, a1;
  #pragma unroll
  for (int e = 0; e < 8; ++e) {
    a0[e] = (bf16_t)(acc0[e] * linv);
    a1[e] = (bf16_t)(acc1[e] * linv);
  }
  f32x4 zero = {0.f, 0.f, 0.f, 0.f};
  const bf16_t* wt = Wt + 3 * 4096;                  // Wo^T
  #pragma unroll
  for (int nt = 0; nt < 4; ++nt) {
    int col = nt * 16 + l16;
    bf16x8 b0 = *(const bf16x8*)&wt[col * 64 + quad * 8];
    bf16x8 b1 = *(const bf16x8*)&wt[col * 64 + 32 + quad * 8];
    f32x4 acc = MFMA32(a0, b0, zero);
    acc = MFMA32(a1, b1, acc);
    float bb = bo[col];
    #pragma unroll
    for (int r = 0; r < 4; ++r) {
      size_t m = (size_t)r0 + quad * 4 + r;
      out[m * 64 + col] = acc[r] + bb + (float)xnb[m * 64 + col];
    }
  }
}

extern "C" void kernel_launch(void* const* d_in, const int* in_sizes, int n_in,
                              void* d_out, int out_size, void* d_ws, size_t ws_size,
                              hipStream_t stream) {
  const float* x     = (const float*)d_in[0];
  const float* gamma = (const float*)d_in[1];
  const float* beta  = (const float*)d_in[2];
  const float* Wq    = (const float*)d_in[3];
  const float* bq    = (const float*)d_in[4];
  const float* Wk    = (const float*)d_in[5];
  const float* bk    = (const float*)d_in[6];
  const float* Wv    = (const float*)d_in[7];
  const float* bv    = (const float*)d_in[8];
  const float* Wo    = (const float*)d_in[9];
  const float* bo    = (const float*)d_in[10];
  float* out = (float*)d_out;

  char* ws = (char*)d_ws;
  bf16_t* xnb   = (bf16_t*)(ws + 0);                    // 2 MB
  bf16_t* qbuf  = (bf16_t*)(ws + (2u  << 20));          // 2 MB
  bf16_t* kbuf  = (bf16_t*)(ws + (4u  << 20));          // 2 MB (swizzled tile images)
  bf16_t* vbuf  = (bf16_t*)(ws + (6u  << 20));          // 2 MB (swizzled tile images)
  bf16_t* Opb   = (bf16_t*)(ws + (8u  << 20));          // 16 MB (8 splits)
  float*  ml    = (float*)(ws + (24u << 20));           // 512 KB
  float2* parts = (float2*)(ws + (25u << 20));          // 2 KB
  bf16_t* Wt    = (bf16_t*)(ws + (25u << 20) + 4096);   // 32 KB

  hipLaunchKernelGGL(gn1w_kernel,  dim3(320),       dim3(256), 0, stream, x, parts, Wq, Wk, Wv, Wo, Wt);
  hipLaunchKernelGGL(gnqkv_kernel, dim3(256),       dim3(256), 0, stream, x, gamma, beta, parts, Wt, bq, bk, bv, xnb, qbuf, kbuf, vbuf);
  hipLaunchKernelGGL(flash_kernel, dim3(4, 32, 8),  dim3(256), 0, stream, qbuf, kbuf, vbuf, Opb, ml);
  hipLaunchKernelGGL(proj_kernel,  dim3(256),       dim3(256), 0, stream, Opb, ml, Wt, bo, xnb, out);
}